// Round 9
// baseline (79.986 us; speedup 1.0000x reference)
//
#include <hip/hip_runtime.h>
#include <cstdint>

#define NB 32
#define NC 512
#define NQ 64
#define ND 512

typedef __attribute__((ext_vector_type(8))) short bf16x8;   // 8 bf16 (4 VGPRs)
typedef __attribute__((ext_vector_type(8))) short short8;
typedef __attribute__((ext_vector_type(4))) float f32x4;

__device__ __forceinline__ short f2bf(float f) {   // RNE f32 -> bf16
  union { float f; unsigned u; } v; v.f = f;
  v.u += 0x7fffu + ((v.u >> 16) & 1u);
  return (short)(v.u >> 16);
}
__device__ __forceinline__ float bf2f(short s) {
  union { float f; unsigned u; } v; v.u = ((unsigned)(unsigned short)s) << 16;
  return v.f;
}

// LDS layout (short units)
#define P_OFF   0        // P bf16 [64 c][72]                (persists through phase B)
#define CM_OFF  4608     // phase A: ctx*w_m bf16 [64][136]
#define QQ_OFF  13312    // phase A: query bf16 [64][136]
#define QT_OFF  4608     // phase B: qT bf16 [128 d][72 q]   (over CM + head of QQ)
#define AQB_OFF 13824    // phase B: aq bf16 [64][136]       (over tail of QQ)
#define SCS_F   11264    // float idx: s_c[64]
#define SQS_F   11328    // s_q[64]
#define PML_F   11392    // partial max [2][64]
#define PEL_F   11520    // partial sum [2][64]
#define SM_SHORTS 23296  // 46592 B

__device__ __forceinline__ int qswz(int dd) {  // q-block XOR swizzle for qT row dd
  return (((dd & 7) ^ ((dd >> 3) & 7)) * 8);
}

// ============ k1: GEMM1 + 2-wave softmax + GEMM2; writes G parts 0,1,2 + m_ws ============
// 512 threads (8 waves): wave w -> c-group (w>>1)*16; q-half / d-half = w&1.
__global__ __launch_bounds__(512) void k1_main(
    const float* __restrict__ ctx, const float* __restrict__ qry,
    const float* __restrict__ W, float* __restrict__ G, float* __restrict__ m_ws)
{
  __shared__ __align__(16) short sm[SM_SHORTS];
  float* smf = (float*)sm;

  const int t    = threadIdx.x;
  const int lane = t & 63;
  const int w    = t >> 6;
  const int ln15 = lane & 15;
  const int g    = lane >> 4;
  const int cw   = (w >> 1) * 16;   // wave's 16 c-rows
  const int qh   = w & 1;           // q-half (GEMM1) / d-half (GEMM2)
  const int qw   = qh * 32;
  // XCD co-location: all 8 c-tiles of a batch share bid%8 (round-robin XCD)
  const int bid  = (int)blockIdx.x;
  const int swz  = (bid & 7) * 32 + (bid >> 3);
  const int b    = swz >> 3;
  const int c0   = (swz & 7) * 64;

  // stager mapping: 8 threads/row, 16 floats each (512 B contiguous row segments)
  const int lr  = t >> 3;           // row 0..63
  const int j16 = (t & 7) * 16;

  f32x4 acc[2] = {};
  float scp = 0.f, sqp = 0.f;

  // ---------- Phase A: S = (ctx*w_m) @ query^T, K=512 in 4 chunks of 128 ----------
  for (int kc = 0; kc < 4; ++kc) {
    const int d0 = kc * 128;
    __syncthreads();
    {
      const float* crow = ctx + ((size_t)(b*NC + c0 + lr))*ND + d0 + j16;
      float4 cv0 = ((const float4*)crow)[0], cv1 = ((const float4*)crow)[1];
      float4 cv2 = ((const float4*)crow)[2], cv3 = ((const float4*)crow)[3];
      const float4 wc0 = *(const float4*)(W + d0 + j16);
      const float4 wc1 = *(const float4*)(W + d0 + j16 + 4);
      const float4 wc2 = *(const float4*)(W + d0 + j16 + 8);
      const float4 wc3 = *(const float4*)(W + d0 + j16 + 12);
      const float4 wm0 = *(const float4*)(W + 2*ND + d0 + j16);
      const float4 wm1 = *(const float4*)(W + 2*ND + d0 + j16 + 4);
      const float4 wm2 = *(const float4*)(W + 2*ND + d0 + j16 + 8);
      const float4 wm3 = *(const float4*)(W + 2*ND + d0 + j16 + 12);
      scp += cv0.x*wc0.x + cv0.y*wc0.y + cv0.z*wc0.z + cv0.w*wc0.w
           + cv1.x*wc1.x + cv1.y*wc1.y + cv1.z*wc1.z + cv1.w*wc1.w
           + cv2.x*wc2.x + cv2.y*wc2.y + cv2.z*wc2.z + cv2.w*wc2.w
           + cv3.x*wc3.x + cv3.y*wc3.y + cv3.z*wc3.z + cv3.w*wc3.w;
      short8 s0, s1;
      s0[0]=f2bf(cv0.x*wm0.x); s0[1]=f2bf(cv0.y*wm0.y); s0[2]=f2bf(cv0.z*wm0.z); s0[3]=f2bf(cv0.w*wm0.w);
      s0[4]=f2bf(cv1.x*wm1.x); s0[5]=f2bf(cv1.y*wm1.y); s0[6]=f2bf(cv1.z*wm1.z); s0[7]=f2bf(cv1.w*wm1.w);
      s1[0]=f2bf(cv2.x*wm2.x); s1[1]=f2bf(cv2.y*wm2.y); s1[2]=f2bf(cv2.z*wm2.z); s1[3]=f2bf(cv2.w*wm2.w);
      s1[4]=f2bf(cv3.x*wm3.x); s1[5]=f2bf(cv3.y*wm3.y); s1[6]=f2bf(cv3.z*wm3.z); s1[7]=f2bf(cv3.w*wm3.w);
      *(short8*)&sm[CM_OFF + lr*136 + j16]     = s0;
      *(short8*)&sm[CM_OFF + lr*136 + j16 + 8] = s1;
      // G part 0 (ctx verbatim) — spreads stores across phase A
      float* gp0 = G + ((size_t)(b*NC + c0 + lr))*2048 + d0 + j16;
      ((float4*)gp0)[0] = cv0; ((float4*)gp0)[1] = cv1;
      ((float4*)gp0)[2] = cv2; ((float4*)gp0)[3] = cv3;
    }
    {
      const float* qrow = qry + ((size_t)(b*NQ + lr))*ND + d0 + j16;
      float4 qv0 = ((const float4*)qrow)[0], qv1 = ((const float4*)qrow)[1];
      float4 qv2 = ((const float4*)qrow)[2], qv3 = ((const float4*)qrow)[3];
      const float4 wq0 = *(const float4*)(W + ND + d0 + j16);
      const float4 wq1 = *(const float4*)(W + ND + d0 + j16 + 4);
      const float4 wq2 = *(const float4*)(W + ND + d0 + j16 + 8);
      const float4 wq3 = *(const float4*)(W + ND + d0 + j16 + 12);
      sqp += qv0.x*wq0.x + qv0.y*wq0.y + qv0.z*wq0.z + qv0.w*wq0.w
           + qv1.x*wq1.x + qv1.y*wq1.y + qv1.z*wq1.z + qv1.w*wq1.w
           + qv2.x*wq2.x + qv2.y*wq2.y + qv2.z*wq2.z + qv2.w*wq2.w
           + qv3.x*wq3.x + qv3.y*wq3.y + qv3.z*wq3.z + qv3.w*wq3.w;
      short8 s0, s1;
      s0[0]=f2bf(qv0.x); s0[1]=f2bf(qv0.y); s0[2]=f2bf(qv0.z); s0[3]=f2bf(qv0.w);
      s0[4]=f2bf(qv1.x); s0[5]=f2bf(qv1.y); s0[6]=f2bf(qv1.z); s0[7]=f2bf(qv1.w);
      s1[0]=f2bf(qv2.x); s1[1]=f2bf(qv2.y); s1[2]=f2bf(qv2.z); s1[3]=f2bf(qv2.w);
      s1[4]=f2bf(qv3.x); s1[5]=f2bf(qv3.y); s1[6]=f2bf(qv3.z); s1[7]=f2bf(qv3.w);
      *(short8*)&sm[QQ_OFF + lr*136 + j16]     = s0;
      *(short8*)&sm[QQ_OFF + lr*136 + j16 + 8] = s1;
    }
    __syncthreads();
    #pragma unroll
    for (int kk = 0; kk < 4; ++kk) {
      const bf16x8 a = *(const bf16x8*)&sm[CM_OFF + (cw + ln15)*136 + kk*32 + g*8];
      #pragma unroll
      for (int n = 0; n < 2; ++n) {
        const bf16x8 bq = *(const bf16x8*)&sm[QQ_OFF + (qw + n*16 + ln15)*136 + kk*32 + g*8];
        acc[n] = __builtin_amdgcn_mfma_f32_16x16x32_bf16(a, bq, acc[n], 0, 0, 0);
      }
    }
  }

  // s_c / s_q: reduce over the 8 stager lanes of each row
  scp += __shfl_xor(scp, 1, 8); scp += __shfl_xor(scp, 2, 8); scp += __shfl_xor(scp, 4, 8);
  sqp += __shfl_xor(sqp, 1, 8); sqp += __shfl_xor(sqp, 2, 8); sqp += __shfl_xor(sqp, 4, 8);
  if ((t & 7) == 0) { smf[SCS_F + lr] = scp; smf[SQS_F + lr] = sqp; }
  __syncthreads();

  // ---------- wave-partial softmax over this wave's 32 q (R7/R8-verified) ----------
  float ev0[4], ev1[4], pmr[4];
  #pragma unroll
  for (int reg = 0; reg < 4; ++reg) {
    float sv0 = acc[0][reg] + smf[SQS_F + qw + ln15];
    float sv1 = acc[1][reg] + smf[SQS_F + qw + 16 + ln15];
    float pm = fmaxf(sv0, sv1);
    pm = fmaxf(pm, __shfl_xor(pm, 1, 16));
    pm = fmaxf(pm, __shfl_xor(pm, 2, 16));
    pm = fmaxf(pm, __shfl_xor(pm, 4, 16));
    pm = fmaxf(pm, __shfl_xor(pm, 8, 16));
    const float e0 = __expf(sv0 - pm), e1 = __expf(sv1 - pm);
    float pe = e0 + e1;
    pe += __shfl_xor(pe, 1, 16); pe += __shfl_xor(pe, 2, 16);
    pe += __shfl_xor(pe, 4, 16); pe += __shfl_xor(pe, 8, 16);
    ev0[reg] = e0; ev1[reg] = e1; pmr[reg] = pm;
    if (ln15 == 0) { smf[PML_F + qh*64 + cw + g*4 + reg] = pm;
                     smf[PEL_F + qh*64 + cw + g*4 + reg] = pe; }
  }
  __syncthreads();   // partials visible

  // ---------- combine the two q-halves; write normalized P (s_c cancels) ----------
  #pragma unroll
  for (int reg = 0; reg < 4; ++reg) {
    const int rloc = cw + g*4 + reg;
    const float m0 = smf[PML_F + rloc], m1 = smf[PML_F + 64 + rloc];
    const float s0 = smf[PEL_F + rloc], s1 = smf[PEL_F + 64 + rloc];
    const float M  = fmaxf(m0, m1);
    const float S  = s0*__expf(m0 - M) + s1*__expf(m1 - M);
    const float f  = __expf(pmr[reg] - M) / S;
    if (qh == 0 && ln15 == 0) m_ws[b*NC + c0 + rloc] = M + smf[SCS_F + rloc];
    sm[P_OFF + rloc*72 + qw + ln15]      = f2bf(ev0[reg] * f);
    sm[P_OFF + rloc*72 + qw + 16 + ln15] = f2bf(ev1[reg] * f);
  }
  __syncthreads();   // P complete before fragment loads

  bf16x8 pa[2];
  pa[0] = *(const bf16x8*)&sm[P_OFF + (cw + ln15)*72 + g*8];
  pa[1] = *(const bf16x8*)&sm[P_OFF + (cw + ln15)*72 + 32 + g*8];

  const int dh = qh;   // wave's 64-d half within each 128-d chunk

  // ---------- Phase B: aq = P @ query (K=64), 4 chunks of 128 d; parts 1,2 ----------
  for (int dc = 0; dc < 4; ++dc) {
    const int d0 = dc * 128;
    __syncthreads();   // prior chunk's qT/aqb reads complete (chunk 0: CM/QQ reads done)
    {
      const float* qrow = qry + ((size_t)(b*NQ + lr))*ND + d0 + j16;
      const float4 a0 = ((const float4*)qrow)[0];
      const float4 a1 = ((const float4*)qrow)[1];
      const float4 a2 = ((const float4*)qrow)[2];
      const float4 a3 = ((const float4*)qrow)[3];
      const float e[16] = {a0.x,a0.y,a0.z,a0.w, a1.x,a1.y,a1.z,a1.w,
                           a2.x,a2.y,a2.z,a2.w, a3.x,a3.y,a3.z,a3.w};
      #pragma unroll
      for (int v = 0; v < 16; ++v) {
        const int dd = j16 + v;
        sm[QT_OFF + dd*72 + (lr ^ qswz(dd))] = f2bf(e[v]);
      }
    }
    __syncthreads();
    f32x4 acc2[4] = {};
    #pragma unroll
    for (int kk = 0; kk < 2; ++kk)
      #pragma unroll
      for (int n = 0; n < 4; ++n) {
        const int dd = dh*64 + n*16 + ln15;
        const bf16x8 bq = *(const bf16x8*)&sm[QT_OFF + dd*72 + ((kk*32 + g*8) ^ qswz(dd))];
        acc2[n] = __builtin_amdgcn_mfma_f32_16x16x32_bf16(pa[kk], bq, acc2[n], 0, 0, 0);
      }
    #pragma unroll
    for (int n = 0; n < 4; ++n)
      #pragma unroll
      for (int reg = 0; reg < 4; ++reg)
        sm[AQB_OFF + (cw + g*4 + reg)*136 + dh*64 + n*16 + ln15] = f2bf(acc2[n][reg]);
    __syncthreads();   // aqb visible
    {
      const short8 ab0 = *(const short8*)&sm[AQB_OFF + lr*136 + j16];
      const short8 ab1 = *(const short8*)&sm[AQB_OFF + lr*136 + j16 + 8];
      float aq[16];
      #pragma unroll
      for (int i = 0; i < 8; ++i) { aq[i] = bf2f(ab0[i]); aq[8+i] = bf2f(ab1[i]); }
      const float* crow = ctx + ((size_t)(b*NC + c0 + lr))*ND + d0 + j16;
      float4 cv0 = ((const float4*)crow)[0], cv1 = ((const float4*)crow)[1];
      float4 cv2 = ((const float4*)crow)[2], cv3 = ((const float4*)crow)[3];
      float* gp = G + ((size_t)(b*NC + c0 + lr))*2048 + d0 + j16;
      ((float4*)(gp + 512))[0] = make_float4(aq[0], aq[1], aq[2], aq[3]);      // part 1
      ((float4*)(gp + 512))[1] = make_float4(aq[4], aq[5], aq[6], aq[7]);
      ((float4*)(gp + 512))[2] = make_float4(aq[8], aq[9], aq[10], aq[11]);
      ((float4*)(gp + 512))[3] = make_float4(aq[12], aq[13], aq[14], aq[15]);
      ((float4*)(gp + 1024))[0] = make_float4(cv0.x*aq[0], cv0.y*aq[1], cv0.z*aq[2], cv0.w*aq[3]);   // part 2
      ((float4*)(gp + 1024))[1] = make_float4(cv1.x*aq[4], cv1.y*aq[5], cv1.z*aq[6], cv1.w*aq[7]);
      ((float4*)(gp + 1024))[2] = make_float4(cv2.x*aq[8], cv2.y*aq[9], cv2.z*aq[10], cv2.w*aq[11]);
      ((float4*)(gp + 1024))[3] = make_float4(cv3.x*aq[12], cv3.y*aq[13], cv3.z*aq[14], cv3.w*aq[15]);
    }
  }
}

// ============ k2: b = softmax_c(m); attended_context (verbatim, proven) ============
__global__ __launch_bounds__(256) void k2_partial(
    const float* __restrict__ ctx, const float* __restrict__ m_ws, float* __restrict__ pc)
{
  const int t  = threadIdx.x;
  const int b  = blockIdx.x >> 4;
  const int ch = blockIdx.x & 15;
  __shared__ float r8[8];
  __shared__ float wts[32];

  const float v0 = m_ws[b*NC + t];
  const float v1 = m_ws[b*NC + 256 + t];
  float mx = fmaxf(v0, v1);
  #pragma unroll
  for (int o = 32; o; o >>= 1) mx = fmaxf(mx, __shfl_xor(mx, o, 64));
  if ((t & 63) == 0) r8[t >> 6] = mx;
  __syncthreads();
  mx = fmaxf(fmaxf(r8[0], r8[1]), fmaxf(r8[2], r8[3]));
  float e = __expf(v0 - mx) + __expf(v1 - mx);
  #pragma unroll
  for (int o = 32; o; o >>= 1) e += __shfl_xor(e, o, 64);
  if ((t & 63) == 0) r8[4 + (t >> 6)] = e;
  __syncthreads();
  const float denom = r8[4] + r8[5] + r8[6] + r8[7];
  if (t < 32) wts[t] = __expf(m_ws[b*NC + ch*32 + t] - mx) / denom;
  __syncthreads();

  float s0 = 0.f, s1 = 0.f;
  const float* base = ctx + ((size_t)(b*NC + ch*32))*ND;
  for (int c = 0; c < 32; ++c) {
    const float w = wts[c];
    s0 += w * base[(size_t)c*ND + t];
    s1 += w * base[(size_t)c*ND + t + 256];
  }
  pc[((size_t)(b*16 + ch))*ND + t]       = s0;
  pc[((size_t)(b*16 + ch))*ND + t + 256] = s1;
}

__global__ __launch_bounds__(512) void k2_reduce(
    const float* __restrict__ pc, float* __restrict__ ac)
{
  const int b = blockIdx.x;
  const int d = threadIdx.x;
  float s = 0.f;
  #pragma unroll
  for (int ch = 0; ch < 16; ++ch) s += pc[((size_t)(b*16 + ch))*ND + d];
  ac[b*ND + d] = s;
}

// ============ k3: G part 3 = ctx * attended_context (verbatim, proven) ============
__global__ __launch_bounds__(256) void k3_part3(
    const float* __restrict__ ctx, const float* __restrict__ ac, float* __restrict__ G)
{
  const size_t e = ((size_t)blockIdx.x*256 + threadIdx.x) * 8;
  const int b = (int)(e >> 18);
  const int r = (int)(e & 262143);
  const int c = r >> 9;
  const int d = r & 511;
  const float4 x0 = *(const float4*)(ctx + e);
  const float4 x1 = *(const float4*)(ctx + e + 4);
  const float4 a0 = *(const float4*)(ac + b*ND + d);
  const float4 a1 = *(const float4*)(ac + b*ND + d + 4);
  float* gp = G + ((size_t)(b*NC + c))*2048 + 1536 + d;
  *(float4*)(gp)     = make_float4(x0.x*a0.x, x0.y*a0.y, x0.z*a0.z, x0.w*a0.w);
  *(float4*)(gp + 4) = make_float4(x1.x*a1.x, x1.y*a1.y, x1.z*a1.z, x1.w*a1.w);
}

extern "C" void kernel_launch(void* const* d_in, const int* in_sizes, int n_in,
                              void* d_out, int out_size, void* d_ws, size_t ws_size,
                              hipStream_t stream)
{
  const float* ctx = (const float*)d_in[0];
  const float* qry = (const float*)d_in[1];
  const float* W   = (const float*)d_in[2];
  float* G = (float*)d_out;

  float* m_ws = (float*)d_ws;            // [32][512]
  float* pc   = m_ws + NB*NC;            // [32][16][512]
  float* ac   = pc + (size_t)NB*16*ND;   // [32][512]

  k1_main   <<<dim3(NB*8),  dim3(512), 0, stream>>>(ctx, qry, W, G, m_ws);
  k2_partial<<<dim3(NB*16), dim3(256), 0, stream>>>(ctx, m_ws, pc);
  k2_reduce <<<dim3(NB),    dim3(512), 0, stream>>>(pc, ac);
  k3_part3  <<<dim3((NB*NC*ND)/(256*8)), dim3(256), 0, stream>>>(ctx, ac, G);
}

// Round 10
// 64.408 us; speedup vs baseline: 1.2419x; 1.2419x over previous
//
#include <hip/hip_runtime.h>
#include <cstdint>

#define NB 32
#define NC 512
#define NQ 64
#define ND 512

typedef __attribute__((ext_vector_type(8))) short bf16x8;   // 8 bf16 (4 VGPRs)
typedef __attribute__((ext_vector_type(8))) short short8;
typedef __attribute__((ext_vector_type(4))) float f32x4;

__device__ __forceinline__ short f2bf(float f) {   // RNE f32 -> bf16
  union { float f; unsigned u; } v; v.f = f;
  v.u += 0x7fffu + ((v.u >> 16) & 1u);
  return (short)(v.u >> 16);
}
__device__ __forceinline__ float bf2f(short s) {
  union { float f; unsigned u; } v; v.u = ((unsigned)(unsigned short)s) << 16;
  return v.f;
}

// ============ kPrep: qT_bf16 [b][d][q] (R6-proven transpose core) ============
__global__ __launch_bounds__(512) void kPrep(
    const float* __restrict__ qry, short* __restrict__ qTbf)
{
  __shared__ short lq[NQ*ND];
  const int b = blockIdx.x;
  const int t = threadIdx.x;
  const int r = t >> 3;            // q row, 8 threads/row
  const int cb = (t & 7) * 64;     // 64-d slice
  const float* qrow = qry + ((size_t)(b*NQ + r))*ND + cb;
  #pragma unroll
  for (int i = 0; i < 16; ++i) {
    const float4 qv = *(const float4*)(qrow + i*4);
    short4 s; s.x=f2bf(qv.x); s.y=f2bf(qv.y); s.z=f2bf(qv.z); s.w=f2bf(qv.w);
    *(short4*)&lq[r*ND + cb + i*4] = s;
  }
  __syncthreads();
  const int d = t;
  short* qTrow = qTbf + ((size_t)(b*ND + d))*NQ;
  #pragma unroll
  for (int j = 0; j < 16; ++j) {
    short4 h4;
    h4.x = lq[(j*4+0)*ND + d];
    h4.y = lq[(j*4+1)*ND + d];
    h4.z = lq[(j*4+2)*ND + d];
    h4.w = lq[(j*4+3)*ND + d];
    *(short4*)&qTrow[j*4] = h4;
  }
}

// ============ kA: GEMM1 + 2-wave softmax; writes P(ws) + m_ws only ============
// 512 blocks (2/CU), 32-c tiles, 4 waves: c-group = w>>1, q-half = w&1.
// LDS (shorts): CM [32][72] @0, QQ [64][72] @2304, P [32][72] @6912;
// floats: SCS@4608[32], SQS@4640[64], PML@4704[64], PEL@4768[64]
#define KA_CM 0
#define KA_QQ 2304
#define KA_P  6912
#define KA_SCS 4608
#define KA_SQS 4640
#define KA_PML 4704
#define KA_PEL 4768
#define KA_SHORTS 9664

__global__ __launch_bounds__(256) void kA(
    const float* __restrict__ ctx, const float* __restrict__ qry,
    const float* __restrict__ W, short* __restrict__ Pws, float* __restrict__ m_ws)
{
  __shared__ __align__(16) short sm[KA_SHORTS];
  float* smf = (float*)sm;

  const int t    = threadIdx.x;
  const int lane = t & 63;
  const int w    = t >> 6;
  const int ln15 = lane & 15;
  const int g    = lane >> 4;
  const int cw   = (w >> 1) * 16;   // wave's 16 c-rows within the 32-tile
  const int qh   = w & 1;           // wave's q-half
  const int qw   = qh * 32;
  const int b    = blockIdx.x >> 4;
  const int c0   = (blockIdx.x & 15) * 32;

  const int lr = t >> 3, j8  = (t & 7) * 8;   // ctx stager: 32 rows x 8 f32
  const int qr = t >> 2, i16 = (t & 3) * 16;  // qry stager: 64 rows x 16 f32

  f32x4 acc[2] = {};
  float scp = 0.f, sqp = 0.f;

  // ---- GEMM1: S = (ctx*w_m) @ query^T, K=512 in 8 chunks (R2/R8-proven staging) ----
  for (int kc = 0; kc < 8; ++kc) {
    const int d0 = kc * 64;
    __syncthreads();
    {
      const float* crow = ctx + ((size_t)(b*NC + c0 + lr))*ND + d0 + j8;
      const float4 ca = *(const float4*)(crow);
      const float4 cb = *(const float4*)(crow + 4);
      const float4 wca = *(const float4*)(W + d0 + j8);
      const float4 wcb = *(const float4*)(W + d0 + j8 + 4);
      const float4 wma = *(const float4*)(W + 2*ND + d0 + j8);
      const float4 wmb = *(const float4*)(W + 2*ND + d0 + j8 + 4);
      scp += ca.x*wca.x + ca.y*wca.y + ca.z*wca.z + ca.w*wca.w
           + cb.x*wcb.x + cb.y*wcb.y + cb.z*wcb.z + cb.w*wcb.w;
      short8 cs;
      cs[0]=f2bf(ca.x*wma.x); cs[1]=f2bf(ca.y*wma.y); cs[2]=f2bf(ca.z*wma.z); cs[3]=f2bf(ca.w*wma.w);
      cs[4]=f2bf(cb.x*wmb.x); cs[5]=f2bf(cb.y*wmb.y); cs[6]=f2bf(cb.z*wmb.z); cs[7]=f2bf(cb.w*wmb.w);
      *(short8*)&sm[KA_CM + lr*72 + j8] = cs;
    }
    {
      const float* qrow = qry + ((size_t)(b*NQ + qr))*ND + d0 + i16;
      const float4 qa = *(const float4*)(qrow);
      const float4 qb = *(const float4*)(qrow + 4);
      const float4 qc = *(const float4*)(qrow + 8);
      const float4 qd = *(const float4*)(qrow + 12);
      const float4 wa  = *(const float4*)(W + ND + d0 + i16);
      const float4 wb  = *(const float4*)(W + ND + d0 + i16 + 4);
      const float4 wc2 = *(const float4*)(W + ND + d0 + i16 + 8);
      const float4 wd  = *(const float4*)(W + ND + d0 + i16 + 12);
      sqp += qa.x*wa.x + qa.y*wa.y + qa.z*wa.z + qa.w*wa.w
           + qb.x*wb.x + qb.y*wb.y + qb.z*wb.z + qb.w*wb.w
           + qc.x*wc2.x + qc.y*wc2.y + qc.z*wc2.z + qc.w*wc2.w
           + qd.x*wd.x + qd.y*wd.y + qd.z*wd.z + qd.w*wd.w;
      short8 s1, s2;
      s1[0]=f2bf(qa.x); s1[1]=f2bf(qa.y); s1[2]=f2bf(qa.z); s1[3]=f2bf(qa.w);
      s1[4]=f2bf(qb.x); s1[5]=f2bf(qb.y); s1[6]=f2bf(qb.z); s1[7]=f2bf(qb.w);
      s2[0]=f2bf(qc.x); s2[1]=f2bf(qc.y); s2[2]=f2bf(qc.z); s2[3]=f2bf(qc.w);
      s2[4]=f2bf(qd.x); s2[5]=f2bf(qd.y); s2[6]=f2bf(qd.z); s2[7]=f2bf(qd.w);
      *(short8*)&sm[KA_QQ + qr*72 + i16]     = s1;
      *(short8*)&sm[KA_QQ + qr*72 + i16 + 8] = s2;
    }
    __syncthreads();
    #pragma unroll
    for (int kk = 0; kk < 2; ++kk) {
      const bf16x8 a = *(const bf16x8*)&sm[KA_CM + (cw + ln15)*72 + kk*32 + g*8];
      #pragma unroll
      for (int n = 0; n < 2; ++n) {
        const bf16x8 bq = *(const bf16x8*)&sm[KA_QQ + (qw + n*16 + ln15)*72 + kk*32 + g*8];
        acc[n] = __builtin_amdgcn_mfma_f32_16x16x32_bf16(a, bq, acc[n], 0, 0, 0);
      }
    }
  }

  // s_c (8-lane rows), s_q (4-lane rows) — R4-proven reductions
  scp += __shfl_xor(scp, 1, 8); scp += __shfl_xor(scp, 2, 8); scp += __shfl_xor(scp, 4, 8);
  if ((t & 7) == 0) smf[KA_SCS + lr] = scp;
  sqp += __shfl_xor(sqp, 1, 4); sqp += __shfl_xor(sqp, 2, 4);
  if ((t & 3) == 0) smf[KA_SQS + qr] = sqp;
  __syncthreads();

  // ---- wave-partial softmax over this wave's 32 q (R7/R8-proven) ----
  float ev0[4], ev1[4], pmr[4];
  #pragma unroll
  for (int reg = 0; reg < 4; ++reg) {
    const int rloc = cw + g*4 + reg;
    float sv0 = acc[0][reg] + smf[KA_SQS + qw + ln15];
    float sv1 = acc[1][reg] + smf[KA_SQS + qw + 16 + ln15];
    float pm = fmaxf(sv0, sv1);
    pm = fmaxf(pm, __shfl_xor(pm, 1, 16));
    pm = fmaxf(pm, __shfl_xor(pm, 2, 16));
    pm = fmaxf(pm, __shfl_xor(pm, 4, 16));
    pm = fmaxf(pm, __shfl_xor(pm, 8, 16));
    const float e0 = __expf(sv0 - pm), e1 = __expf(sv1 - pm);
    float pe = e0 + e1;
    pe += __shfl_xor(pe, 1, 16); pe += __shfl_xor(pe, 2, 16);
    pe += __shfl_xor(pe, 4, 16); pe += __shfl_xor(pe, 8, 16);
    ev0[reg] = e0; ev1[reg] = e1; pmr[reg] = pm;
    if (ln15 == 0) { smf[KA_PML + qh*32 + rloc] = pm;
                     smf[KA_PEL + qh*32 + rloc] = pe; }
  }
  __syncthreads();

  // ---- combine q-halves; write normalized P (s_c cancels; added to stored rowmax) ----
  #pragma unroll
  for (int reg = 0; reg < 4; ++reg) {
    const int rloc = cw + g*4 + reg;
    const float m0 = smf[KA_PML + rloc], m1 = smf[KA_PML + 32 + rloc];
    const float s0 = smf[KA_PEL + rloc], s1 = smf[KA_PEL + 32 + rloc];
    const float M  = fmaxf(m0, m1);
    const float S  = s0*__expf(m0 - M) + s1*__expf(m1 - M);
    const float f  = __expf(pmr[reg] - M) / S;
    if (qh == 0 && ln15 == 0) m_ws[b*NC + c0 + rloc] = M + smf[KA_SCS + rloc];
    sm[KA_P + rloc*72 + qw + ln15]      = f2bf(ev0[reg] * f);
    sm[KA_P + rloc*72 + qw + 16 + ln15] = f2bf(ev1[reg] * f);
  }
  __syncthreads();   // P complete

  // coalesced P writeout: [b][c][64 q] bf16
  {
    const int row = t >> 3, col8 = (t & 7) * 8;
    const short8 v = *(const short8*)&sm[KA_P + row*72 + col8];
    *(short8*)&Pws[((size_t)(b*NC + c0 + row))*NQ + col8] = v;
  }
}

// ============ k2: b = softmax_c(m); attended_context (verbatim, proven) ============
__global__ __launch_bounds__(256) void k2_partial(
    const float* __restrict__ ctx, const float* __restrict__ m_ws, float* __restrict__ pc)
{
  const int t  = threadIdx.x;
  const int b  = blockIdx.x >> 4;
  const int ch = blockIdx.x & 15;
  __shared__ float r8[8];
  __shared__ float wts[32];

  const float v0 = m_ws[b*NC + t];
  const float v1 = m_ws[b*NC + 256 + t];
  float mx = fmaxf(v0, v1);
  #pragma unroll
  for (int o = 32; o; o >>= 1) mx = fmaxf(mx, __shfl_xor(mx, o, 64));
  if ((t & 63) == 0) r8[t >> 6] = mx;
  __syncthreads();
  mx = fmaxf(fmaxf(r8[0], r8[1]), fmaxf(r8[2], r8[3]));
  float e = __expf(v0 - mx) + __expf(v1 - mx);
  #pragma unroll
  for (int o = 32; o; o >>= 1) e += __shfl_xor(e, o, 64);
  if ((t & 63) == 0) r8[4 + (t >> 6)] = e;
  __syncthreads();
  const float denom = r8[4] + r8[5] + r8[6] + r8[7];
  if (t < 32) wts[t] = __expf(m_ws[b*NC + ch*32 + t] - mx) / denom;
  __syncthreads();

  float s0 = 0.f, s1 = 0.f;
  const float* base = ctx + ((size_t)(b*NC + ch*32))*ND;
  for (int c = 0; c < 32; ++c) {
    const float w = wts[c];
    s0 += w * base[(size_t)c*ND + t];
    s1 += w * base[(size_t)c*ND + t + 256];
  }
  pc[((size_t)(b*16 + ch))*ND + t]       = s0;
  pc[((size_t)(b*16 + ch))*ND + t + 256] = s1;
}

__global__ __launch_bounds__(512) void k2_reduce(
    const float* __restrict__ pc, float* __restrict__ ac)
{
  const int b = blockIdx.x;
  const int d = threadIdx.x;
  float s = 0.f;
  #pragma unroll
  for (int ch = 0; ch < 16; ++ch) s += pc[((size_t)(b*16 + ch))*ND + d];
  ac[b*ND + d] = s;
}

// ============ kB: GEMM2 + barrier-free stream of ALL FOUR G parts ============
// 512 blocks (2/CU), 256 thr. LDS (shorts): qt [256 d][72 q] @0,
// P [32][72] @18432, aqf bf16 [4 waves][32][72] @20736; acl f32[512] @f14976.
#define KB_QT 0
#define KB_P  18432
#define KB_AQ 20736
#define KB_ACF 14976
#define KB_SHORTS 30976

__global__ __launch_bounds__(256) void kB(
    const float* __restrict__ ctx, const short* __restrict__ qTbf,
    const short* __restrict__ Pws, const float* __restrict__ ac,
    float* __restrict__ G)
{
  __shared__ __align__(16) short sm[KB_SHORTS];
  float* smf = (float*)sm;

  const int t    = threadIdx.x;
  const int lane = t & 63;
  const int w    = t >> 6;        // wave: d-quad within each 256-d half
  const int ln15 = lane & 15;
  const int g    = lane >> 4;
  const int b    = blockIdx.x >> 4;
  const int c0   = (blockIdx.x & 15) * 32;

  // ---- stage P, ac, qt(half 0) ----
  {
    const int row = t >> 3, col8 = (t & 7) * 8;
    *(short8*)&sm[KB_P + row*72 + col8] =
        *(const short8*)&Pws[((size_t)(b*NC + c0 + row))*NQ + col8];
  }
  smf[KB_ACF + t]       = ac[b*ND + t];
  smf[KB_ACF + 256 + t] = ac[b*ND + 256 + t];
  {
    const int rr = t >> 3, col8 = (t & 7) * 8;
    #pragma unroll
    for (int ii = 0; ii < 8; ++ii) {
      const int dd = ii*32 + rr;
      *(short8*)&sm[KB_QT + dd*72 + col8] =
          *(const short8*)&qTbf[((size_t)(b*ND + dd))*NQ + col8];
    }
  }
  __syncthreads();

  // P fragments (A-operand), loaded once
  bf16x8 pa[2][2];
  #pragma unroll
  for (int cf = 0; cf < 2; ++cf)
    #pragma unroll
    for (int kk = 0; kk < 2; ++kk)
      pa[cf][kk] = *(const bf16x8*)&sm[KB_P + (cf*16 + ln15)*72 + kk*32 + g*8];

  #pragma unroll
  for (int h = 0; h < 2; ++h) {
    // ---- GEMM2 for this 256-d half: wave's 64-d quad ----
    f32x4 acc2[2][4] = {};
    #pragma unroll
    for (int kk = 0; kk < 2; ++kk)
      #pragma unroll
      for (int n = 0; n < 4; ++n) {
        const int dd = w*64 + n*16 + ln15;
        const bf16x8 bq = *(const bf16x8*)&sm[KB_QT + dd*72 + kk*32 + g*8];
        acc2[0][n] = __builtin_amdgcn_mfma_f32_16x16x32_bf16(pa[0][kk], bq, acc2[0][n], 0, 0, 0);
        acc2[1][n] = __builtin_amdgcn_mfma_f32_16x16x32_bf16(pa[1][kk], bq, acc2[1][n], 0, 0, 0);
      }
    // aqf (bf16), per-wave region
    #pragma unroll
    for (int cf = 0; cf < 2; ++cf)
      #pragma unroll
      for (int n = 0; n < 4; ++n)
        #pragma unroll
        for (int reg = 0; reg < 4; ++reg)
          sm[KB_AQ + w*2304 + (cf*16 + g*4 + reg)*72 + n*16 + ln15] = f2bf(acc2[cf][n][reg]);
    __syncthreads();   // aqf visible; qt(h) MFMA reads done

    if (h == 0) {      // stage qt(half 1) — overlaps the half-0 stream
      const int rr = t >> 3, col8 = (t & 7) * 8;
      #pragma unroll
      for (int ii = 0; ii < 8; ++ii) {
        const int dd = ii*32 + rr;
        *(short8*)&sm[KB_QT + dd*72 + col8] =
            *(const short8*)&qTbf[((size_t)(b*ND + 256 + dd))*NQ + col8];
      }
    }

    // ---- barrier-free stream: 32 rows x 256 d, parts 0,1,2,3 ----
    #pragma unroll
    for (int i = 0; i < 8; ++i) {
      const int task = i*16 + (t >> 4);
      const int r  = task & 31;
      const int sg = task >> 5;                 // 64-d seg == producing wave
      const int dglob = h*256 + sg*64 + (t & 15)*4;
      const short4 a4 = *(const short4*)&sm[KB_AQ + sg*2304 + r*72 + (t & 15)*4];
      const float4 cv = *(const float4*)(ctx + ((size_t)(b*NC + c0 + r))*ND + dglob);
      const float4 acv = *(const float4*)&smf[KB_ACF + dglob];
      const float q0 = bf2f(a4.x), q1 = bf2f(a4.y), q2 = bf2f(a4.z), q3 = bf2f(a4.w);
      float* gp = G + ((size_t)(b*NC + c0 + r))*2048 + dglob;
      *(float4*)(gp)        = cv;                                                  // part 0
      *(float4*)(gp + 512)  = make_float4(q0, q1, q2, q3);                         // part 1
      *(float4*)(gp + 1024) = make_float4(cv.x*q0, cv.y*q1, cv.z*q2, cv.w*q3);     // part 2
      *(float4*)(gp + 1536) = make_float4(cv.x*acv.x, cv.y*acv.y,
                                          cv.z*acv.z, cv.w*acv.w);                 // part 3
    }
    if (h == 0) __syncthreads();   // qt1 staged; aqf half-0 reads done
  }
}

extern "C" void kernel_launch(void* const* d_in, const int* in_sizes, int n_in,
                              void* d_out, int out_size, void* d_ws, size_t ws_size,
                              hipStream_t stream)
{
  const float* ctx = (const float*)d_in[0];
  const float* qry = (const float*)d_in[1];
  const float* W   = (const float*)d_in[2];
  float* G = (float*)d_out;

  float* ws   = (float*)d_ws;
  float* m_ws = ws;                          // [32][512]
  float* pc   = ws + 16384;                  // [32][16][512]
  float* ac   = ws + 278528;                 // [32][512]
  short* qTbf = (short*)(ws + 294912);       // [32][512][64] bf16
  short* Pws  = qTbf + (size_t)NB*ND*NQ;     // [32][512][64] bf16

  kPrep     <<<dim3(NB),    dim3(512), 0, stream>>>(qry, qTbf);
  kA        <<<dim3(NB*16), dim3(256), 0, stream>>>(ctx, qry, W, Pws, m_ws);
  k2_partial<<<dim3(NB*16), dim3(256), 0, stream>>>(ctx, m_ws, pc);
  k2_reduce <<<dim3(NB),    dim3(512), 0, stream>>>(pc, ac);
  kB        <<<dim3(NB*16), dim3(256), 0, stream>>>(ctx, qTbf, Pws, ac, G);
}